// Round 10
// baseline (207.107 us; speedup 1.0000x reference)
//
#include <hip/hip_runtime.h>
#include <cmath>

namespace {
constexpr float kE   = 3130.0f;
constexpr float kNu  = 0.37f;
constexpr float kSy0 = 64.8f;
constexpr float kH   = 100.0f;
constexpr float kG   = kE / (2.0f * (1.0f + kNu));
constexpr float kLam = kE * kNu / ((1.0f + kNu) * (1.0f - 2.0f * kNu));
constexpr float kC   = kE / ((1.0f + kNu) * (1.0f - 2.0f * kNu));
constexpr float kC11 = kC * (1.0f - kNu);
constexpr float kC12 = kC * kNu;
constexpr float kC2  = 3.0f * kG / (3.0f * kG + kH);  // 3G/(3G+H)
constexpr float kC3  = kH / (3.0f * kG + kH);         // 1 - kC2
constexpr int kS  = 2048;
constexpr int kT  = 16;
constexpr int kNBLK = kS / kT;   // 128
constexpr int kLs = 192;
constexpr float kSq15  = 1.224744871391589f;  // sqrt(1.5)
constexpr float kSq3   = 1.732050807568877f;  // sqrt(3)
constexpr float kISq15 = 1.0f / kSq15;
constexpr float kISq3  = 1.0f / kSq3;
constexpr int kPartStride = 128 * 2048 * 3;   // floats per partial slice
}

typedef __fp16 half2_t __attribute__((ext_vector_type(2)));
typedef float f4_t __attribute__((ext_vector_type(4)));

__device__ __forceinline__ unsigned pk16(float a, float b) {
    half2_t h = __builtin_amdgcn_cvt_pkrtz(a, b);
    return __builtin_bit_cast(unsigned, h);
}
__device__ __forceinline__ float up16lo(unsigned u) {
    half2_t h = __builtin_bit_cast(half2_t, u);
    return (float)h.x;
}
__device__ __forceinline__ float up16hi(unsigned u) {
    half2_t h = __builtin_bit_cast(half2_t, u);
    return (float)h.y;
}

template<int CTRL, int RM, int BM>
__device__ __forceinline__ float dppmov(float v) {
    return __int_as_float(
        __builtin_amdgcn_update_dpp(0, __float_as_int(v), CTRL, RM, BM, false));
}
// wave64 sum, result in lane 63
__device__ __forceinline__ float wave_sum63(float v) {
    v += dppmov<0x111, 0xf, 0xf>(v);
    v += dppmov<0x112, 0xf, 0xf>(v);
    v += dppmov<0x114, 0xf, 0xf>(v);
    v += dppmov<0x118, 0xf, 0xf>(v);
    v += dppmov<0x142, 0xa, 0xf>(v);
    v += dppmov<0x143, 0xc, 0xf>(v);
    return v;
}
// quad_perm DPP move (4-lane group reduce helper)
template<int CTRL>
__device__ __forceinline__ float qdpp(float v) {
    return __int_as_float(
        __builtin_amdgcn_update_dpp(0, __float_as_int(v), CTRL, 0xF, 0xF, true));
}

__device__ __forceinline__ float softplusf(float v) {
    return log1pf(expf(v));
}

// pre-differenced strain-driver dx stream: (b, t) -> 3 floats
__device__ __align__(16) float g_dx[128 * 2048 * 3];   // 3.1 MB

// ===================== Kernel A: dx pre-difference ==========================
__global__ __launch_bounds__(256, 4)
void j2_dx(const float* __restrict__ x)
{
    const int gid = blockIdx.x * 256 + threadIdx.x;   // (b,t), 0..262143
    const int t = gid & 2047;
    const float* xe = x + (size_t)gid * 3;
    const float a0 = xe[0], a1 = xe[1], a2 = xe[2];
    float p0 = 0.f, p1 = 0.f, p2 = 0.f;
    if (t != 0) { p0 = xe[-3]; p1 = xe[-2]; p2 = xe[-1]; }
    float* o = g_dx + (size_t)gid * 3;
    o[0] = a0 - p0; o[1] = a1 - p1; o[2] = a2 - p2;
}

// ============ Kernel B: fused lane-parallel scan + in-LDS einsum ============
// Grid (128 b, 4 qtr) x 192 threads (3 waves).
//   wave 0: 4-lane-per-chain component scan of 16 chains; writes s-hat
//           (f16-packed, 2 steps/word) to LDS double buffer.
//   waves 1,2: each covers 8 of the 16 chains; lane (t,o) computes the
//           partial output r = Mv.x(t) + sum_8chains spp.s_hat and stores it
//           to a per-(qtr,half) partial slice in d_ws. No cross-lane reduce.
// One __syncthreads per phase (double-buffered LDS).
__global__ __launch_bounds__(192, 1)
void j2_fused(const float* __restrict__ x,
              const float* __restrict__ W1,
              const float* __restrict__ W2,
              float* __restrict__ partials)
{
    __shared__ unsigned sg[2][64 * 8];   // [buf][slot(kc*4+c)*8 + t2]

    const int b   = blockIdx.x;
    const int qtr = blockIdx.y;
    const int w   = threadIdx.x >> 6;   // 0..2
    const int ln  = threadIdx.x & 63;

    if (w == 0) {
        // ------------------------- scan wave --------------------------------
        const int kc = ln >> 2;             // local chain 0..15
        const int c  = ln & 3;              // component
        const int kg = qtr * 16 + kc;       // chain within batch

        float gv[3];
#pragma unroll
        for (int f = 0; f < 3; ++f) {
            const float w0 = W1[(3 * kg + 0) * 3 + f];
            const float w1 = W1[(3 * kg + 1) * 3 + f];
            const float w2 = W1[(3 * kg + 2) * 3 + f];
            const float e0 = kC11 * w0 + kC12 * w1;
            const float e1 = kC12 * w0 + kC11 * w1;
            const float lv = kLam * (w0 + w1);
            const float g0 = kSq15 * (2.0f * e0 - e1 - lv) * (1.0f / 3.0f);
            const float g1 = kSq15 * (2.0f * e1 - e0 - lv) * (1.0f / 3.0f);
            const float g2 = kSq3 * kG * w2;
            const float gz = -(g0 + g1);
            gv[f] = (c == 0) ? g0 : (c == 1) ? g1 : (c == 2) ? g2 : gz;
        }

        const float* db = g_dx + (size_t)b * (kS * 3);
        float s = 0.f, y = kSy0, c2y = kC2 * kSy0;

        auto loadw = [&](f4_t* dst, int p) {
            const f4_t* s4 = reinterpret_cast<const f4_t*>(db + p * 48);
#pragma unroll
            for (int i = 0; i < 12; ++i) dst[i] = s4[i];
        };

        auto body = [&](const f4_t* Wd, int p) {
            float u[kT];
#pragma unroll
            for (int t = 0; t < kT; ++t) {
                const float d0 = Wd[(3 * t + 0) >> 2][(3 * t + 0) & 3];
                const float d1 = Wd[(3 * t + 1) >> 2][(3 * t + 1) & 3];
                const float d2 = Wd[(3 * t + 2) >> 2][(3 * t + 2) & 3];
                u[t] = fmaf(gv[0], d0, fmaf(gv[1], d1, gv[2] * d2));
            }
            unsigned* dstb = &sg[p & 1][ln * 8];
            float se = 0.f;
#pragma unroll
            for (int t = 0; t < kT; ++t) {
                const float st = s + u[t];
                float pp = fmaf(st, st, 2.5e-13f);
                pp += qdpp<0xB1>(pp);
                pp += qdpp<0x4E>(pp);
                const float rq  = __builtin_amdgcn_rsqf(pp);
                const float fac = fminf(fmaf(c2y, rq, kC3), 1.0f);
                s = fac * st;
                const float qv = pp * rq;
                y = fmaxf(y, fmaf(kC3, qv, c2y));
                c2y = kC2 * y;
                if ((t & 1) == 0) se = s;
                else              dstb[t >> 1] = pk16(se, s);
            }
        };

        f4_t A[12], B[12];
        loadw(A, 0);
        // phase p: scan block p (p<128); barrier; consumers read block p-1.
        for (int p = 0; p <= kNBLK; ++p) {
            if (p < kNBLK) {
                if (p + 1 < kNBLK) {
                    if (p & 1) loadw(A, p + 1); else loadw(B, p + 1);
                }
                body((p & 1) ? B : A, p);
            }
            __syncthreads();
        }
    } else {
        // ----------------------- consumer waves -----------------------------
        const int half = w - 1;             // 0: chains 0-7, 1: chains 8-15
        const bool act = (ln < 48);
        const int t  = act ? (ln / 3) : 15; // 0..15
        const int o  = act ? (ln % 3) : 0;  // output component
        const int t2 = t >> 1, th = t & 1;
        const int kcl0 = half * 8;          // WG-local chain base
        const int kg0  = qtr * 16 + kcl0;   // batch chain base

        // per-lane constants: spp[8][3], Mv[3] (mean-stress folded)
        float spp[8][3], Mv0 = 0.f, Mv1 = 0.f, Mv2 = 0.f;
#pragma unroll
        for (int j = 0; j < 8; ++j) {
            const int kg = kg0 + j;
            const float a0 = softplusf(W2[o * kLs + 3 * kg + 0]);
            const float a1 = softplusf(W2[o * kLs + 3 * kg + 1]);
            const float a2 = softplusf(W2[o * kLs + 3 * kg + 2]);
            spp[j][0] = a0 * kISq15;
            spp[j][1] = a1 * kISq15;
            spp[j][2] = a2 * kISq3;
            const float so = a0 + a1;
#pragma unroll
            for (int f = 0; f < 3; ++f) {
                const float w0 = W1[(3 * kg + 0) * 3 + f];
                const float w1 = W1[(3 * kg + 1) * 3 + f];
                const float e0 = kC11 * w0 + kC12 * w1;
                const float e1 = kC12 * w0 + kC11 * w1;
                const float lv = kLam * (w0 + w1);
                const float mv = (e0 + e1 + lv) * (1.0f / 3.0f);
                const float c_ = so * mv;
                if (f == 0) Mv0 += c_;
                else if (f == 1) Mv1 += c_;
                else Mv2 += c_;
            }
        }

        const float* xb = x + (size_t)b * (kS * 3);
        float* pout = partials + (size_t)(qtr * 2 + half) * kPartStride
                      + (size_t)b * (kS * 3);

        for (int p = 0; p <= kNBLK; ++p) {
            __syncthreads();
            if (p >= kNBLK) break;
            // consume block p (written this phase by producer? No:
            // producer wrote block p BEFORE this barrier) -> block p ready.
            const int tabs = p * kT + t;
            const float x0 = xb[tabs * 3 + 0];
            const float x1 = xb[tabs * 3 + 1];
            const float x2 = xb[tabs * 3 + 2];
            float r = fmaf(Mv0, x0, fmaf(Mv1, x1, Mv2 * x2));
            const unsigned* sb = &sg[p & 1][0];
#pragma unroll
            for (int j = 0; j < 8; ++j) {
                const int base = ((kcl0 + j) * 4) * 8 + t2;
                const unsigned u0 = sb[base];
                const unsigned u1 = sb[base + 8];
                const unsigned u2 = sb[base + 16];
                const float s0 = th ? up16hi(u0) : up16lo(u0);
                const float s1 = th ? up16hi(u1) : up16lo(u1);
                const float s2 = th ? up16hi(u2) : up16lo(u2);
                r = fmaf(spp[j][0], s0,
                    fmaf(spp[j][1], s1, fmaf(spp[j][2], s2, r)));
            }
            if (act) pout[tabs * 3 + o] = r;
        }
    }
}

// ================== Kernel D: sum the 8 partial slices ======================
__global__ __launch_bounds__(256, 4)
void j2_final(const float* __restrict__ partials, float* __restrict__ out)
{
    const int gid = blockIdx.x * 256 + threadIdx.x;   // 0..786431
    float acc = partials[gid];
#pragma unroll
    for (int h = 1; h < 8; ++h)
        acc += partials[(size_t)h * kPartStride + gid];
    out[gid] = acc;
}

// ================== Fallback: known-good R2 3-wave kernel ===================
__global__ __launch_bounds__(192, 1)
void j2_pc_kernel(const float* __restrict__ x,
                  const float* __restrict__ W1,
                  const float* __restrict__ W2,
                  float* __restrict__ out)
{
    __shared__ float4 ubuf[2][kT][64];
    __shared__ float4 sgbuf[2][kT][64];

    const int b = blockIdx.x;
    const int w = threadIdx.x >> 6;
    const int k = threadIdx.x & 63;

    const float* xb = x + (size_t)b * (kS * 3);
    float* ob = out + (size_t)b * (kS * 3);

    float e0[3], e1[3], e2[3], lv[3], sp[3][3];
    if (w != 0) {
        float wr[3][3];
#pragma unroll
        for (int j = 0; j < 3; ++j)
#pragma unroll
            for (int f = 0; f < 3; ++f)
                wr[j][f] = W1[(3 * k + j) * 3 + f];
#pragma unroll
        for (int f = 0; f < 3; ++f) {
            e0[f] = kC11 * wr[0][f] + kC12 * wr[1][f];
            e1[f] = kC12 * wr[0][f] + kC11 * wr[1][f];
            e2[f] = kG * wr[2][f];
            lv[f] = kLam * (wr[0][f] + wr[1][f]);
        }
#pragma unroll
        for (int o = 0; o < 3; ++o)
#pragma unroll
            for (int j = 0; j < 3; ++j) {
                float v = W2[o * kLs + 3 * k + j];
                sp[o][j] = log1pf(expf(v));
            }
    }

    float sg0 = 0.f, sg1 = 0.f, sg2 = 0.f, szz = 0.f;
    float y = kSy0;
    const int tlo = (w == 2) ? 8 : 0;
    constexpr float kInv3GH = 1.0f / (3.0f * kG + kH);
    constexpr float k3G = 3.0f * kG;

    for (int phase = 0; phase <= kNBLK + 1; ++phase) {
        if (w == 0) {
            if (phase >= 1 && phase <= kNBLK) {
                const int blk = phase - 1, pb = blk & 1;
                float4 u[kT];
#pragma unroll
                for (int t = 0; t < kT; ++t) u[t] = ubuf[pb][t][k];
#pragma unroll
                for (int t = 0; t < kT; ++t) {
                    const float t0 = sg0 + u[t].x;
                    const float t1 = sg1 + u[t].y;
                    const float t2 = sg2 + u[t].z;
                    const float tz = szz + u[t].w;
                    const float pm  = (t0 + t1 + tz) * (1.0f / 3.0f);
                    const float dxx = t0 - pm, dyy = t1 - pm, dzz = tz - pm;
                    const float sa  = fmaf(dxx, dxx, dyy * dyy);
                    const float sb  = fmaf(dzz, dzz, (2.0f * t2) * t2);
                    const float q2  = fmaf(1.5f, sa + sb, 1e-12f);
                    const float qq  = __builtin_amdgcn_sqrtf(q2);
                    const float rq  = __builtin_amdgcn_rcpf(qq);
                    const float f   = qq - y;
                    const float dg  = (f > 0.0f) ? f * kInv3GH : 0.0f;
                    y = fmaf(kH, dg, y);
                    const float fac = fmaf(-(k3G * dg), rq, 1.0f);
                    sg0 = fmaf(fac, dxx, pm);
                    sg1 = fmaf(fac, dyy, pm);
                    sg2 = fac * t2;
                    szz = fmaf(fac, dzz, pm);
                    sgbuf[pb][t][k] = make_float4(sg0, sg1, sg2, 0.f);
                }
            }
        } else {
            if (phase < kNBLK) {
                const int p = phase, pb = p & 1;
                float xv[28];
                if (w == 1) {
                    if (p == 0) {
                        xv[0] = xv[1] = xv[2] = xv[3] = 0.f;
                        const float4* s4 = reinterpret_cast<const float4*>(xb);
#pragma unroll
                        for (int i = 0; i < 6; ++i) {
                            float4 v = s4[i];
                            xv[4 + 4 * i] = v.x; xv[5 + 4 * i] = v.y;
                            xv[6 + 4 * i] = v.z; xv[7 + 4 * i] = v.w;
                        }
                    } else {
                        const float4* s4 =
                            reinterpret_cast<const float4*>(xb + p * 48 - 4);
#pragma unroll
                        for (int i = 0; i < 7; ++i) {
                            float4 v = s4[i];
                            xv[4 * i]     = v.x; xv[4 * i + 1] = v.y;
                            xv[4 * i + 2] = v.z; xv[4 * i + 3] = v.w;
                        }
                    }
                } else {
                    const float4* s4 =
                        reinterpret_cast<const float4*>(xb + p * 48 + 20);
#pragma unroll
                    for (int i = 0; i < 7; ++i) {
                        float4 v = s4[i];
                        xv[4 * i]     = v.x; xv[4 * i + 1] = v.y;
                        xv[4 * i + 2] = v.z; xv[4 * i + 3] = v.w;
                    }
                }
                const int tbase = (w == 2) ? 8 : 0;
#pragma unroll
                for (int t = 0; t < 8; ++t) {
                    const float dx0 = xv[3 * t + 4] - xv[3 * t + 1];
                    const float dx1 = xv[3 * t + 5] - xv[3 * t + 2];
                    const float dx2 = xv[3 * t + 6] - xv[3 * t + 3];
                    float4 u;
                    u.x = fmaf(e0[0], dx0, fmaf(e0[1], dx1, e0[2] * dx2));
                    u.y = fmaf(e1[0], dx0, fmaf(e1[1], dx1, e1[2] * dx2));
                    u.z = fmaf(e2[0], dx0, fmaf(e2[1], dx1, e2[2] * dx2));
                    u.w = fmaf(lv[0], dx0, fmaf(lv[1], dx1, lv[2] * dx2));
                    ubuf[pb][tbase + t][k] = u;
                }
            }
            if (phase >= 2) {
                const int q = phase - 2, qb = q & 1;
                const int tbase = tlo;
                float r[24];
#pragma unroll
                for (int t = 0; t < 8; ++t) {
                    float4 s = sgbuf[qb][tbase + t][k];
                    r[3 * t]     = fmaf(sp[0][0], s.x, fmaf(sp[0][1], s.y, sp[0][2] * s.z));
                    r[3 * t + 1] = fmaf(sp[1][0], s.x, fmaf(sp[1][1], s.y, sp[1][2] * s.z));
                    r[3 * t + 2] = fmaf(sp[2][0], s.x, fmaf(sp[2][1], s.y, sp[2][2] * s.z));
                }
#pragma unroll
                for (int v = 0; v < 24; ++v) r[v] = wave_sum63(r[v]);
                if (k == 63) {
                    float4* o4 = reinterpret_cast<float4*>(ob + q * 48 + tbase * 3);
#pragma unroll
                    for (int i = 0; i < 6; ++i)
                        o4[i] = make_float4(r[4 * i], r[4 * i + 1],
                                            r[4 * i + 2], r[4 * i + 3]);
                }
            }
        }
        __syncthreads();
    }
}

extern "C" void kernel_launch(void* const* d_in, const int* in_sizes, int n_in,
                              void* d_out, int out_size, void* d_ws, size_t ws_size,
                              hipStream_t stream) {
    const float* x  = (const float*)d_in[0];   // (128, 2048, 3)
    const float* W1 = (const float*)d_in[1];   // (192, 3)
    const float* W2 = (const float*)d_in[2];   // (3, 192)
    float* out = (float*)d_out;                // (128, 2048, 3)

    const size_t need = (size_t)8 * kPartStride * sizeof(float);  // 25.2 MB
    if (ws_size >= need) {
        float* partials = (float*)d_ws;
        j2_dx<<<dim3(1024), dim3(256), 0, stream>>>(x);
        j2_fused<<<dim3(128, 4), dim3(192), 0, stream>>>(x, W1, W2, partials);
        j2_final<<<dim3(3072), dim3(256), 0, stream>>>(partials, out);
    } else {
        j2_pc_kernel<<<dim3(128), dim3(192), 0, stream>>>(x, W1, W2, out);
    }
}